// Round 7
// baseline (3123.563 us; speedup 1.0000x reference)
//
#include <hip/hip_runtime.h>
#include <stdint.h>

// GRU: SEQ=512, BATCH=64, IN=512, HID=1024. fp32 in/out, bf16 MFMA internally.
//
// Phase 1: gx = x @ W_ih^T + b_ih  (bf16, [512][64][3072] in ws)
// Phase 2: persistent plain-launch kernel, 256 blocks. __launch_bounds__(256,2)
//          caps VGPR at 256 -> 2 blocks/CU capacity -> all 256 blocks
//          co-resident even under uneven dispatch. Block b = (cg=b&63,
//          bh=b>>6): h-cols [16cg,16cg+16) x batch rows [16bh,16bh+16).
//          4 waves split K (256 each); partials reduced via 12KB LDS.
//          Group-local barrier: only the 64 blocks sharing bh communicate
//          (h dataflow is group-closed: block (cg,bh) reads rows written
//          exclusively by {(cg',bh)}).
//
// Round-7 (r6 was an infra failure -- no pytest output; its payload is
// untested). Race background: r3->r5 changed ZERO fp ops yet absmax moved
// 0.0039 -> 0.0154 -> 0.0273 => nondeterminism => the h-store -> flag ->
// poll -> read chain leaks: a plain sc0sc1 store's vmcnt-ack can fire
// before the line is ordered at the LLC, so a remote reader can see the
// flag before the h data. r0-r3's global barrier masked it with slack;
// r4's group barrier removed the slack.
//   FIX (hardened vs r6): h store is a RETURNING __hip_atomic_exchange,
//   result consumed by an opaque asm sink -- the returning form's vmcnt
//   ack requires data BACK FROM the coherence point, so the vmcnt(0)
//   drain at barrier (B) proves h is globally visible before the flag
//   store issues. (r6's discarded result let LLVM emit the no-rtn swap,
//   whose ack semantics are unproven.)
//   Guard tightened to 1<<17 (~0.1s): any sync failure reports
//   wrong-fast instead of tripping container watchdogs.
// Kept from r5/r6 (arithmetically inert perf items):
//   1. W_hh fragments in registers via opaque asm keep-alive (VGPR ~200).
//   2. Own old-h carried in-register (hwpack) across steps.
//   3. Next-step gx loads issued under the barrier poll.
//   No cache fences anywhere -> W_hh/gx stay warm in L1/L2.

#define SEQ    512
#define BATCH  64
#define IN_DIM 512
#define HID    1024
#define G3     3072
#define NBLK   256

typedef __bf16 bf16x8 __attribute__((ext_vector_type(8)));
typedef short  s16x8  __attribute__((ext_vector_type(8)));
typedef float  f32x4  __attribute__((ext_vector_type(4)));
typedef unsigned int u32x4 __attribute__((ext_vector_type(4)));

__device__ __forceinline__ float bf2f(unsigned int u) {
    union { unsigned int i; float f; } c; c.i = u << 16; return c.f;
}
__device__ __forceinline__ unsigned short f2bf(float f) {
    union { float f; unsigned int i; } c; c.f = f;
    unsigned int u = c.i;
    u += 0x7fffu + ((u >> 16) & 1u);   // RNE
    return (unsigned short)(u >> 16);
}

// ---------------------------------------------------------------- converts
__global__ void cvt_f32_bf16(const float* __restrict__ in,
                             unsigned short* __restrict__ out, int n) {
    int i = (blockIdx.x * 256 + threadIdx.x) * 4;
    if (i + 3 < n) {
        float4 v = *(const float4*)(in + i);
        ushort4 o;
        o.x = f2bf(v.x); o.y = f2bf(v.y); o.z = f2bf(v.z); o.w = f2bf(v.w);
        *(ushort4*)(out + i) = o;
    }
}

__global__ void init_state(unsigned int* __restrict__ h0,
                           unsigned int* __restrict__ h1,
                           unsigned int* __restrict__ flags) {
    int i = blockIdx.x * 256 + threadIdx.x;
    if (i < BATCH * HID) { h0[i] = 0u; h1[i] = 0u; }
    if (i < NBLK * 4)    flags[i] = 0u;   // 4 groups x 64 flags x 16B
}

// ---------------------------------------------------------------- gx GEMM
// C[32768][3072] = A[32768][512] @ W[3072][512]^T + b_ih, operands direct
// from global (bf16, L2/L3-resident), 128x128 block tile, 4 waves of 64x64.
__global__ __launch_bounds__(256) void gx_gemm(
    const unsigned short* __restrict__ xb,
    const unsigned short* __restrict__ wb,
    const float* __restrict__ bih,
    unsigned short* __restrict__ gx) {
    const int lane = threadIdx.x & 63;
    const int wv   = threadIdx.x >> 6;
    const int r    = lane & 15;
    const int quad = lane >> 4;
    const int m0 = blockIdx.x * 128 + (wv & 1) * 64;
    const int n0 = blockIdx.y * 128 + (wv >> 1) * 64;

    f32x4 acc[4][4];
#pragma unroll
    for (int a = 0; a < 4; a++)
#pragma unroll
        for (int b = 0; b < 4; b++) acc[a][b] = (f32x4){0.f, 0.f, 0.f, 0.f};

    const unsigned short* ap[4];
    const unsigned short* bp[4];
#pragma unroll
    for (int mi = 0; mi < 4; mi++)
        ap[mi] = xb + (size_t)(m0 + mi * 16 + r) * IN_DIM + quad * 8;
#pragma unroll
    for (int ni = 0; ni < 4; ni++)
        bp[ni] = wb + (size_t)(n0 + ni * 16 + r) * IN_DIM + quad * 8;

#pragma unroll 4
    for (int kk = 0; kk < IN_DIM / 32; kk++) {
        bf16x8 af[4], bf_[4];
#pragma unroll
        for (int mi = 0; mi < 4; mi++)
            af[mi] = __builtin_bit_cast(bf16x8, *(const s16x8*)(ap[mi] + kk * 32));
#pragma unroll
        for (int ni = 0; ni < 4; ni++)
            bf_[ni] = __builtin_bit_cast(bf16x8, *(const s16x8*)(bp[ni] + kk * 32));
#pragma unroll
        for (int mi = 0; mi < 4; mi++)
#pragma unroll
            for (int ni = 0; ni < 4; ni++)
                acc[mi][ni] = __builtin_amdgcn_mfma_f32_16x16x32_bf16(
                    af[mi], bf_[ni], acc[mi][ni], 0, 0, 0);
    }

#pragma unroll
    for (int ni = 0; ni < 4; ni++) {
        const int col = n0 + ni * 16 + r;
        const float bias = bih[col];
#pragma unroll
        for (int mi = 0; mi < 4; mi++)
#pragma unroll
            for (int i = 0; i < 4; i++) {
                const int row = m0 + mi * 16 + quad * 4 + i;  // C/D m89 layout
                gx[(size_t)row * G3 + col] = f2bf(acc[mi][ni][i] + bias);
            }
    }
}

// batched LLC-coherent loads (L1 bypass, serviced coherently)
#define HL16(dst, OFF)                                                    \
    asm volatile("global_load_dwordx4 %0, %1, off offset:" OFF " sc0 sc1" \
                 : "=&v"(dst) : "v"(hbase))
#define SL4(dst, BASE)                                                    \
    asm volatile("global_load_dword %0, %1, off sc0 sc1"                  \
                 : "=&v"(dst) : "v"(BASE))

// ---------------------------------------------------------------- recurrence
// 256 blocks x 256 threads, plain launch (2-blocks/CU capacity, co-resident).
__global__ __launch_bounds__(256, 2) void gru_seq(
    const unsigned short* __restrict__ whb,   // [3072][1024] bf16
    const float* __restrict__ bhh,            // [3072]
    const unsigned short* __restrict__ gxb,   // [512][64][3072] bf16
    unsigned int* __restrict__ h0,            // packed (hi<<16|lo) h, dbuf
    unsigned int* __restrict__ h1,
    unsigned int* __restrict__ flags,         // [4 groups][64] stride-16B
    float* __restrict__ out) {
    const int lane = threadIdx.x & 63;
    const int wv   = threadIdx.x >> 6;
    const int r    = lane & 15;
    const int quad = lane >> 4;
    const int cg   = blockIdx.x & 63;
    const int bh   = blockIdx.x >> 6;
    const int J0   = cg * 16;     // h-col base
    const int R0   = bh * 16;     // batch row base
    const int k0   = wv * 256;    // this wave's K quarter

    __shared__ float red[4][3][4][64];   // [wave][gate][acc_i][lane], 12 KB
    __shared__ int dead;                 // barrier-timeout latch
    if (threadIdx.x == 0) dead = 0;
    __syncthreads();

    // ---- W_hh fragments: load once, FORCE register residency -----------
    const unsigned short* wrp = whb + (size_t)(J0 + r) * HID + k0 + quad * 8;
    const unsigned short* wzp = wrp + (size_t)HID * HID;
    const unsigned short* wnp = wrp + (size_t)2 * HID * HID;
    u32x4 wRv[8], wZv[8], wNv[8];        // 96 VGPRs live across the t-loop
#pragma unroll
    for (int kk = 0; kk < 8; kk++) {
        wRv[kk] = *(const u32x4*)(wrp + kk * 32);
        wZv[kk] = *(const u32x4*)(wzp + kk * 32);
        wNv[kk] = *(const u32x4*)(wnp + kk * 32);
    }
#pragma unroll
    for (int kk = 0; kk < 8; kk++) {
        // opaque "modification": rematerializing the load is now illegal,
        // so the values must stay resident in VGPRs for the whole loop.
        asm volatile("" : "+v"(wRv[kk]), "+v"(wZv[kk]), "+v"(wNv[kk]));
    }
    const float bhr = bhh[J0 + r];
    const float bhz = bhh[HID + J0 + r];
    const float bhn = bhh[2 * HID + J0 + r];

    const int    arow = R0 + r;                 // A-frag batch row
    const int    erow = R0 + quad * 4 + wv;     // epilogue row (i = wv)
    const size_t hidx = (size_t)erow * HID + J0 + r;
    // group-local poll base: this bh-group's 64 flags (16B stride each)
    const unsigned int* fbase = flags + (size_t)(bh * 256 + lane * 4);
    const int myflag = bh * 256 + cg * 4;

    // gx operands for step t, loaded one step ahead (under the poll)
    const unsigned short* gpr = gxb + (size_t)erow * G3 + J0 + r;
    float xr = bf2f(gpr[0]);
    float xz = bf2f(gpr[HID]);
    float xn = bf2f(gpr[2 * HID]);
    unsigned int hwpack = 0u;            // own old-h (t-1 store), h0 = 0

#pragma unroll 1
    for (int t = 0; t < SEQ; t++) {
        const unsigned int* cur = (t & 1) ? h1 : h0;
        unsigned int*       nxt = (t & 1) ? h0 : h1;

        // ---- batched coherent h loads: ONE latency exposure ------------
        const unsigned int* hbase = cur + (size_t)arow * HID + k0 + quad * 8;
        u32x4 q[16];
        HL16(q[0],  "0");    HL16(q[1],  "16");
        HL16(q[2],  "128");  HL16(q[3],  "144");
        HL16(q[4],  "256");  HL16(q[5],  "272");
        HL16(q[6],  "384");  HL16(q[7],  "400");
        HL16(q[8],  "512");  HL16(q[9],  "528");
        HL16(q[10], "640");  HL16(q[11], "656");
        HL16(q[12], "768");  HL16(q[13], "784");
        HL16(q[14], "896");  HL16(q[15], "912");
        asm volatile("s_waitcnt vmcnt(0)" ::: "memory");
        __builtin_amdgcn_sched_barrier(0);   // rule #18: pin consumers below

        f32x4 aR = {0.f, 0.f, 0.f, 0.f};
        f32x4 aZ = {0.f, 0.f, 0.f, 0.f};
        f32x4 aN = {0.f, 0.f, 0.f, 0.f};
#pragma unroll
        for (int kk = 0; kk < 8; kk++) {
            const u32x4 qa = q[2 * kk];
            const u32x4 qb = q[2 * kk + 1];
            u32x4 ahw, alw;
            ahw[0] = __builtin_amdgcn_perm(qa[1], qa[0], 0x07060302u);
            alw[0] = __builtin_amdgcn_perm(qa[1], qa[0], 0x05040100u);
            ahw[1] = __builtin_amdgcn_perm(qa[3], qa[2], 0x07060302u);
            alw[1] = __builtin_amdgcn_perm(qa[3], qa[2], 0x05040100u);
            ahw[2] = __builtin_amdgcn_perm(qb[1], qb[0], 0x07060302u);
            alw[2] = __builtin_amdgcn_perm(qb[1], qb[0], 0x05040100u);
            ahw[3] = __builtin_amdgcn_perm(qb[3], qb[2], 0x07060302u);
            alw[3] = __builtin_amdgcn_perm(qb[3], qb[2], 0x05040100u);
            bf16x8 ah = __builtin_bit_cast(bf16x8, ahw);
            bf16x8 al = __builtin_bit_cast(bf16x8, alw);
            bf16x8 fr = __builtin_bit_cast(bf16x8, wRv[kk]);
            bf16x8 fz = __builtin_bit_cast(bf16x8, wZv[kk]);
            bf16x8 fn = __builtin_bit_cast(bf16x8, wNv[kk]);
            // pure-register MFMA chain; 3 independent ops between dep pairs
            aR = __builtin_amdgcn_mfma_f32_16x16x32_bf16(ah, fr, aR, 0, 0, 0);
            aZ = __builtin_amdgcn_mfma_f32_16x16x32_bf16(ah, fz, aZ, 0, 0, 0);
            aN = __builtin_amdgcn_mfma_f32_16x16x32_bf16(ah, fn, aN, 0, 0, 0);
            aR = __builtin_amdgcn_mfma_f32_16x16x32_bf16(al, fr, aR, 0, 0, 0);
            aZ = __builtin_amdgcn_mfma_f32_16x16x32_bf16(al, fz, aZ, 0, 0, 0);
            aN = __builtin_amdgcn_mfma_f32_16x16x32_bf16(al, fn, aN, 0, 0, 0);
        }

        // K-partials -> LDS ([wave][gate][i][lane]: 4B lane stride, no conflicts)
#pragma unroll
        for (int i = 0; i < 4; i++) {
            red[wv][0][i][lane] = aR[i];
            red[wv][1][i][lane] = aZ[i];
            red[wv][2][i][lane] = aN[i];
        }
        __syncthreads();   // (A) partials visible

        // epilogue: wave wv handles accumulator slot i = wv (rows quad*4+wv)
        const float sR = red[0][0][wv][lane] + red[1][0][wv][lane]
                       + red[2][0][wv][lane] + red[3][0][wv][lane];
        const float sZ = red[0][1][wv][lane] + red[1][1][wv][lane]
                       + red[2][1][wv][lane] + red[3][1][wv][lane];
        const float sN = red[0][2][wv][lane] + red[1][2][wv][lane]
                       + red[2][2][wv][lane] + red[3][2][wv][lane];
        const float hold = bf2f(hwpack >> 16) + bf2f(hwpack & 0xffffu);
        const float rg = 1.f / (1.f + __expf(-(xr + sR + bhr)));
        const float zg = 1.f / (1.f + __expf(-(xz + sZ + bhz)));
        const float e2 = __expf(2.f * (xn + rg * (sN + bhn)));
        const float ng = 1.f - 2.f / (e2 + 1.f);
        const float hn = (1.f - zg) * ng + zg * hold;
        const unsigned int uhi = f2bf(hn);
        const unsigned int ulo = f2bf(hn - bf2f(uhi));
        hwpack = (uhi << 16) | ulo;          // carry own old-h in-register
        // RACE FIX (hardened): RETURNING atomic swap -- vmcnt ack requires
        // the old value back from the coherence point, so the vmcnt(0)
        // drain at barrier (B) proves h is globally visible before the
        // flag store issues. The asm sink forces the returning variant.
        {
            unsigned int oldswp = __hip_atomic_exchange(
                nxt + hidx, hwpack, __ATOMIC_RELAXED, __HIP_MEMORY_SCOPE_AGENT);
            asm volatile("" :: "v"(oldswp));   // consume -> no no-rtn demotion
        }

        if (t != SEQ - 1) {
            // (B): every wave's s_waitcnt vmcnt(0) at this barrier drains the
            // h swap round-trip -> flag signal is ordered after h data.
            __syncthreads();
            if (threadIdx.x == 0)
                __hip_atomic_store(flags + myflag, (unsigned int)(t + 1),
                                   __ATOMIC_RELAXED, __HIP_MEMORY_SCOPE_AGENT);
            // off the drain path: out store + next-step gx prefetch both
            // complete under the poll
            out[(size_t)t * (BATCH * HID) + hidx] = hn;
            gpr += BATCH * G3;
            xr = bf2f(gpr[0]);
            xz = bf2f(gpr[HID]);
            xn = bf2f(gpr[2 * HID]);
            if (wv == 0 && !dead) {
                const unsigned int tgt = (unsigned int)(t + 1);
                int guard = 0;
                for (;;) {
                    unsigned int f0;          // ONE group-local poll load
                    SL4(f0, fbase);
                    asm volatile("s_waitcnt vmcnt(0)" ::: "memory");
                    __builtin_amdgcn_sched_barrier(0);
                    if (__all(f0 >= tgt)) break;
                    if (++guard > (1 << 17)) {   // ~0.1s: sync failsafe ->
                        if (lane == 0) dead = 1; // report wrong-FAST, no hang
                        break;
                    }
                    __builtin_amdgcn_s_sleep(1);
                }
            }
            __syncthreads();   // (C) release all waves into step t+1
        } else {
            out[(size_t)t * (BATCH * HID) + hidx] = hn;
            out[(size_t)SEQ * (BATCH * HID) + hidx] = hn;
        }
    }
}

// ---------------------------------------------------------------- launch
extern "C" void kernel_launch(void* const* d_in, const int* in_sizes, int n_in,
                              void* d_out, int out_size, void* d_ws, size_t ws_size,
                              hipStream_t stream) {
    const float* x   = (const float*)d_in[0];
    const float* Wih = (const float*)d_in[1];
    const float* Whh = (const float*)d_in[2];
    const float* bih = (const float*)d_in[3];
    const float* bhh = (const float*)d_in[4];
    float* out = (float*)d_out;

    char* ws = (char*)d_ws;
    size_t off = 0;
    auto alloc = [&](size_t bytes) {
        char* p = ws + off;
        off += (bytes + 255) & ~(size_t)255;
        return p;
    };
    unsigned int*   flags = (unsigned int*)alloc((size_t)NBLK * 16);
    unsigned int*   h0    = (unsigned int*)alloc((size_t)BATCH * HID * 4);
    unsigned int*   h1    = (unsigned int*)alloc((size_t)BATCH * HID * 4);
    unsigned short* xb    = (unsigned short*)alloc((size_t)SEQ * BATCH * IN_DIM * 2);
    unsigned short* wihb  = (unsigned short*)alloc((size_t)G3 * IN_DIM * 2);
    unsigned short* whhb  = (unsigned short*)alloc((size_t)G3 * HID * 2);
    unsigned short* gxb   = (unsigned short*)alloc((size_t)SEQ * BATCH * G3 * 2);
    (void)ws_size; (void)in_sizes; (void)n_in; (void)out_size;

    init_state<<<(BATCH * HID + 255) / 256, 256, 0, stream>>>(h0, h1, flags);
    cvt_f32_bf16<<<(SEQ * BATCH * IN_DIM / 4) / 256, 256, 0, stream>>>(
        x, xb, SEQ * BATCH * IN_DIM);
    cvt_f32_bf16<<<(G3 * IN_DIM / 4) / 256, 256, 0, stream>>>(Wih, wihb, G3 * IN_DIM);
    cvt_f32_bf16<<<(G3 * HID / 4) / 256, 256, 0, stream>>>(Whh, whhb, G3 * HID);
    gx_gemm<<<dim3(SEQ * BATCH / 128, G3 / 128), 256, 0, stream>>>(
        xb, wihb, bih, gxb);

    gru_seq<<<dim3(NBLK), dim3(256), 0, stream>>>(
        whhb, bhh, gxb, h0, h1, flags, out);
}